// Round 4
// baseline (401.416 us; speedup 1.0000x reference)
//
#include <hip/hip_runtime.h>

// LuGre friction cell, B=4096 x T=2048 serial steps, S=1, H=64.
// Round 9: payload via DPP quad-broadcast -> LDS round-trip deleted.
//  - r8 counters: wall 151 cyc/step, LDS pipe ~112 cyc/CU-step (75%):
//    2 waves x (2 broadcast ds_read_b128 + gather + writes). The payload
//    round-trip through LDS is the structural cost.
//  - New: 4 lanes/seq (16 seqs/wave, 256 waves, 1/CU). Lane q mkpres step
//    4n+q, keeps the 7-float payload IN REGISTERS; chain step t reads it via
//    v_mov_dpp quad_perm broadcast (VALU, 2 cyc, zero DS traffic, zero
//    latency). preBuf deleted; DS pipe = table gather only (1 instr-set per
//    4 steps, same per-seq-step cost as r8).
//  - x prefetch depth 5 blocks (~1000+ cyc), gather depth 2, all in regs;
//    main loop unrolled x4 so queue rotations rename away.
//  - Per-step math / mkpre / gather / F bit-identical to r8.

#define DT 1e-3f
#define NV 256
#define VMINF (-6.6f)
#define VMAXF (6.6f)
#define ZAF   (2.56f)   // Chebyshev half-range in sz

// ---- stage 1: MLP node values + quartic solve -> global tabA/tabB ----------
__global__ __launch_bounds__(320) void coef_kernel(
    const float* __restrict__ W1,   // [2,64]
    const float* __restrict__ b1,   // [64]
    const float* __restrict__ W2,   // [64]
    const float* __restrict__ b2,   // [1]
    float4* __restrict__ tabA,      // [NV] (c0,c1,c2,c3) * -DT
    float*  __restrict__ tabB)      // [NV] c4 * -DT
{
    __shared__ float fsh[5];
    const int iv = blockIdx.x;          // v-node (256 blocks)
    const int j  = threadIdx.x >> 6;    // sz-node (5 waves/block)
    const int h  = threadIdx.x & 63;    // hidden unit
    const float v = VMINF + iv * ((VMAXF - VMINF) / (NV - 1));
    const float pn = 0.95105651629f * ZAF;   // cos(pi/10)*A
    const float qn = 0.58778525229f * ZAF;   // cos(3pi/10)*A
    const float szv = (j == 0) ? pn : (j == 1) ? -pn
                    : (j == 2) ? qn : (j == 3) ? -qn : 0.f;
    const float pre = fmaf(v, W1[h], fmaf(szv, W1[64 + h], b1[h]));
    float c = W2[h] * tanhf(pre);
#pragma unroll
    for (int o = 32; o; o >>= 1) c += __shfl_down(c, o);
    if (h == 0) {
        const float y = c + b2[0];
        fsh[j] = fmaxf(y, 0.f) + log1pf(expf(-fabsf(y)));  // softplus
    }
    __syncthreads();
    if (threadIdx.x == 0) {
        const float f0 = fsh[0], f1 = fsh[1], f2 = fsh[2], f3 = fsh[3];
        const float c0 = fsh[4];
        const float P = pn * pn, Q = qn * qn;
        const float ep = 0.5f * (f0 + f1) - c0;
        const float eq = 0.5f * (f2 + f3) - c0;
        const float op = 0.5f * (f0 - f1);
        const float oq = 0.5f * (f2 - f3);
        const float invPQ = 1.f / (P - Q);
        const float c4 = (ep / P - eq / Q) * invPQ;
        const float c2 = ep / P - c4 * P;
        const float c3 = (op / pn - oq / qn) * invPQ;
        const float c1 = op / pn - c3 * P;
        tabA[iv] = make_float4(-DT * c0, -DT * c1, -DT * c2, -DT * c3);
        tabB[iv] = -DT * c4;
    }
}

// quad_perm broadcast of lane L's value to all 4 lanes of each quad (VALU)
template <int L>
__device__ __forceinline__ float qb(float v) {
    constexpr int ctrl = L | (L << 2) | (L << 4) | (L << 6);  // [L,L,L,L]
    const int s = __float_as_int(v);
    return __int_as_float(
        __builtin_amdgcn_update_dpp(s, s, ctrl, 0xf, 0xf, false));
}

// ---- stage 2: main recurrence ----------------------------------------------
__global__ __launch_bounds__(64) void lugre_kernel(
    const float* __restrict__ x,       // [B, T, 3]
    const float* __restrict__ sigma1,
    const float* __restrict__ sigma2,
    const float* __restrict__ alpha_p,
    const float* __restrict__ vs_p,
    const float4* __restrict__ tabA,   // [NV]
    const float*  __restrict__ tabB,   // [NV]
    float* __restrict__ out,           // [B, T]
    int B, int T)
{
    __shared__ float4 sA[NV];                       // 4096 B lerp table
    __shared__ float  sB[NV];                       // 1024 B

    const int tid = threadIdx.x;       // 64 threads = 1 wave
    for (int i = tid; i < NV; i += 64) { sA[i] = tabA[i]; sB[i] = tabB[i]; }
    __syncthreads();                   // single wave: ~free

    const int laneq = tid & 3;         // lane within quad = step owner
    const int quad  = tid >> 2;        // 16 quads (sequences) per wave
    const int b     = blockIdx.x * 16 + quad;
    const int NM    = T / 4;           // 512 mini-blocks of 4 steps

    const float LOG2E = 1.4426950408889634f;
    const float s1v    = fabsf(sigma1[0]);
    const float s2v    = fabsf(sigma2[0]);
    const float s12    = s1v + s2v;
    const float alpha  = alpha_p[0];
    const float inv_vs = 1.0f / vs_p[0];
    const float SVC    = (NV - 1) / (VMAXF - VMINF);
    const float VOFF   = -VMINF * SVC;    // 127.5
    const float IMAX   = 254.999f;

    const float* __restrict__ xb = x + (size_t)b * T * 3;
    float* __restrict__ outb = out + (size_t)b * T;

    const bool own[4] = { laneq == 0, laneq == 1, laneq == 2, laneq == 3 };

    // LDS lerp-table gather for this lane's step of a block (off the chain)
    auto gather = [&](float v, float4& A0, float4& A1,
                      float& B0, float& B1, float& fr) {
        const float fvr = __builtin_amdgcn_fmed3f(fmaf(v, SVC, VOFF), 0.f, IMAX);
        const float fvf = floorf(fvr);
        fr = fvr - fvf;
        const int iv = (int)fvf;
        A0 = sA[iv]; A1 = sA[iv + 1];
        B0 = sB[iv]; B1 = sB[iv + 1];
    };

    // mkpre for this lane's step: lerp + premultiply -> 7-float payload in
    // regs (e0..e4,k,fs) + lane-own F constants (Q, Sv). Bit-identical to r8.
    auto finish = [&](float v, float fc, float fs,
                      const float4& A0, const float4& A1,
                      float B0, float B1, float fr,
                      float& e0, float& e1, float& e2, float& e3, float& e4,
                      float& kk, float& ff, float& oQ, float& oSv) {
        const float av = fabsf(v);
        const float u  = av * inv_vs;
        const float lg = __builtin_amdgcn_logf(u);            // log2(u)
        const float pw = __builtin_amdgcn_exp2f(alpha * lg);  // u^alpha
        const float w_ = __builtin_amdgcn_exp2f(-LOG2E * pw); // exp(-u^alpha)
        const float g  = fmaf(fs - fc, w_, fc);
        kk = copysignf(g, v);
        const float avg = av * __builtin_amdgcn_rcpf(g);
        e0 = fmaf(fr, A1.x - A0.x, A0.x) * avg;
        e1 = fmaf(fr, A1.y - A0.y, A0.y) * avg;
        e2 = fmaf(fr, A1.z - A0.z, A0.z) * avg;
        e3 = fmaf(fr, A1.w - A0.w, A0.w) * avg;
        e4 = fmaf(fr, B1 - B0, B0) * avg;
        ff = fs;
        oQ  = -(s1v * avg);      // F = oQ*szn + (oSv + clip(szn))
        oSv = s12 * v;
    };

    // x queue: xq0..xq3 = blocks n+1..n+4 at top of iter n (3 floats each)
    float x0v, x0c, x0f, x1v, x1c, x1f, x2v, x2c, x2f, x3v, x3c, x3f;
    // gather stage for block n+1 (used by this iter's mkpre)
    float4 gA0, gA1; float gB0, gB1, gfr;
    // current payload (block n), lane-local regs (dpp-broadcast per step)
    float ce0, ce1, ce2, ce3, ce4, ck, cf, cQ, cSv;

    // prologue: x for blocks 0..4; payload for block 0; gather for block 1
    {
        const float* p0 = xb + 3 * laneq;
        const float b0v = p0[0], b0c = p0[1], b0f = p0[2];
        const float* p1 = xb + 12 + 3 * laneq;
        x0v = p1[0]; x0c = p1[1]; x0f = p1[2];
        const float* p2 = xb + 24 + 3 * laneq;
        x1v = p2[0]; x1c = p2[1]; x1f = p2[2];
        const float* p3 = xb + 36 + 3 * laneq;
        x2v = p3[0]; x2c = p3[1]; x2f = p3[2];
        const float* p4 = xb + 48 + 3 * laneq;
        x3v = p4[0]; x3c = p4[1]; x3f = p4[2];

        float4 aA0, aA1; float aB0, aB1, afr;
        gather(b0v, aA0, aA1, aB0, aB1, afr);
        finish(b0v, b0c, b0f, aA0, aA1, aB0, aB1, afr,
               ce0, ce1, ce2, ce3, ce4, ck, cf, cQ, cSv);
        gather(x0v, gA0, gA1, gB0, gB1, gfr);
    }

    float sz = 0.f;

#define STEP(t) {                                                   \
        const float e0 = qb<t>(ce0), e1 = qb<t>(ce1);               \
        const float e2 = qb<t>(ce2), e3 = qb<t>(ce3);               \
        const float e4 = qb<t>(ce4), kk = qb<t>(ck), ff = qb<t>(cf);\
        const float t1  = fmaf(e1, sz, e0);                         \
        const float t2  = fmaf(e3, sz, e2);                         \
        const float z2  = sz * sz;                                  \
        const float smk = sz - kk;                                  \
        const float t12 = fmaf(t2, z2, t1);                         \
        const float z4  = z2 * z2;                                  \
        const float xd  = fmaf(e4, z4, t12);                        \
        const float u_  = fmaf(xd, 0.5f, 1.f);                      \
        const float w_  = xd * u_;                                  \
        const float szn = fmaf(smk, w_, sz);                        \
        sz = __builtin_amdgcn_fmed3f(szn, -ff, ff);                 \
        kept = own[t] ? szn : kept; }

#pragma unroll 4
    for (int n = 0; n < NM; ++n) {
        // x load for block n+5 (lands >=3 iters before first use)
        const int ml = (n + 5 < NM) ? n + 5 : NM - 1;
        const float* xp = xb + 12 * ml + 3 * laneq;
        const float lv = xp[0], lc = xp[1], lf = xp[2];

        // table gather for block n+2 (lane-own v, resident in x1*)
        float4 nA0, nA1; float nB0, nB1, nfr;
        gather(x1v, nA0, nA1, nB0, nB1, nfr);

        // mkpre for block n+1 -> next payload (off the sz chain)
        float ne0, ne1, ne2, ne3, ne4, nk, nf, nQ, nSv;
        finish(x0v, x0c, x0f, gA0, gA1, gB0, gB1, gfr,
               ne0, ne1, ne2, ne3, ne4, nk, nf, nQ, nSv);

        // 4 chain steps on block n's payload (dpp broadcast per step)
        float kept = 0.f;
        STEP(0); STEP(1); STEP(2); STEP(3);

        // F for this lane's step of block n, from lane-own constants
        const float cl = __builtin_amdgcn_fmed3f(kept, -cf, cf);
        outb[4 * n + laneq] = fmaf(cQ, kept, cSv + cl);

        // rotate pipelines (renamed away under unroll-4)
        x0v = x1v; x0c = x1c; x0f = x1f;
        x1v = x2v; x1c = x2c; x1f = x2f;
        x2v = x3v; x2c = x3c; x2f = x3f;
        x3v = lv;  x3c = lc;  x3f = lf;
        gA0 = nA0; gA1 = nA1; gB0 = nB0; gB1 = nB1; gfr = nfr;
        ce0 = ne0; ce1 = ne1; ce2 = ne2; ce3 = ne3; ce4 = ne4;
        ck = nk; cf = nf; cQ = nQ; cSv = nSv;
    }
#undef STEP
}

extern "C" void kernel_launch(void* const* d_in, const int* in_sizes, int n_in,
                              void* d_out, int out_size, void* d_ws, size_t ws_size,
                              hipStream_t stream) {
    const float* x  = (const float*)d_in[0];
    const float* s1 = (const float*)d_in[1];
    const float* s2 = (const float*)d_in[2];
    const float* al = (const float*)d_in[3];
    const float* vs = (const float*)d_in[4];
    const float* W1 = (const float*)d_in[5];
    const float* b1 = (const float*)d_in[6];
    const float* W2 = (const float*)d_in[7];
    const float* b2 = (const float*)d_in[8];
    float* out = (float*)d_out;

    float4* tabA = (float4*)d_ws;                       // 4096 B
    float*  tabB = (float*)((char*)d_ws + NV * 16);     // 1024 B

    const int T = 2048;
    const int B = out_size / T;               // 4096

    coef_kernel<<<NV, 320, 0, stream>>>(W1, b1, W2, b2, tabA, tabB);
    lugre_kernel<<<B / 16, 64, 0, stream>>>(x, s1, s2, al, vs, tabA, tabB,
                                            out, B, T);
}

// Round 5
// 248.758 us; speedup vs baseline: 1.6137x; 1.6137x over previous
//
#include <hip/hip_runtime.h>

// LuGre friction cell, B=4096 x T=2048 serial steps, S=1, H=64.
// Round 10: row_newbcast payload broadcast + 4 waves/CU.
//  - r9 failed on occupancy, not on the DPP idea: VGPR=36 proved the compiler
//    collapsed the register pipelines, and at 1 wave/CU (2.9% occ) every
//    exposed latency hit the wall (VALUBusy 11%). LDS-conflict drop (8.8M ->
//    2.3M) confirmed the zero-LDS payload works.
//  - New: 16 lanes/seq, 4 seqs/wave, 1024 waves = 4 waves/CU (r6's TLP).
//    Lane t mkpres step t of each 16-step block, payload (e0..e4,k,fs) stays
//    in registers; chain step t reads it via v_mov_dpp row_newbcast:t
//    (gfx90a+ DPP16, ctrl 0x150|t) -- VALU pipe, no LDS storage, no latency.
//  - DS pipe now carries ONLY the v-indexed lerp-table gather (1 per 16
//    steps per lane, issued ~1.5 blocks early). x prefetch depth 3 blocks.
//  - Per-step math / mkpre / gather / F bit-identical to r8/r9.

#define DT 1e-3f
#define NV 256
#define VMINF (-6.6f)
#define VMAXF (6.6f)
#define ZAF   (2.56f)   // Chebyshev half-range in sz

// ---- stage 1: MLP node values + quartic solve -> global tabA/tabB ----------
__global__ __launch_bounds__(320) void coef_kernel(
    const float* __restrict__ W1,   // [2,64]
    const float* __restrict__ b1,   // [64]
    const float* __restrict__ W2,   // [64]
    const float* __restrict__ b2,   // [1]
    float4* __restrict__ tabA,      // [NV] (c0,c1,c2,c3) * -DT
    float*  __restrict__ tabB)      // [NV] c4 * -DT
{
    __shared__ float fsh[5];
    const int iv = blockIdx.x;          // v-node (256 blocks)
    const int j  = threadIdx.x >> 6;    // sz-node (5 waves/block)
    const int h  = threadIdx.x & 63;    // hidden unit
    const float v = VMINF + iv * ((VMAXF - VMINF) / (NV - 1));
    const float pn = 0.95105651629f * ZAF;   // cos(pi/10)*A
    const float qn = 0.58778525229f * ZAF;   // cos(3pi/10)*A
    const float szv = (j == 0) ? pn : (j == 1) ? -pn
                    : (j == 2) ? qn : (j == 3) ? -qn : 0.f;
    const float pre = fmaf(v, W1[h], fmaf(szv, W1[64 + h], b1[h]));
    float c = W2[h] * tanhf(pre);
#pragma unroll
    for (int o = 32; o; o >>= 1) c += __shfl_down(c, o);
    if (h == 0) {
        const float y = c + b2[0];
        fsh[j] = fmaxf(y, 0.f) + log1pf(expf(-fabsf(y)));  // softplus
    }
    __syncthreads();
    if (threadIdx.x == 0) {
        const float f0 = fsh[0], f1 = fsh[1], f2 = fsh[2], f3 = fsh[3];
        const float c0 = fsh[4];
        const float P = pn * pn, Q = qn * qn;
        const float ep = 0.5f * (f0 + f1) - c0;
        const float eq = 0.5f * (f2 + f3) - c0;
        const float op = 0.5f * (f0 - f1);
        const float oq = 0.5f * (f2 - f3);
        const float invPQ = 1.f / (P - Q);
        const float c4 = (ep / P - eq / Q) * invPQ;
        const float c2 = ep / P - c4 * P;
        const float c3 = (op / pn - oq / qn) * invPQ;
        const float c1 = op / pn - c3 * P;
        tabA[iv] = make_float4(-DT * c0, -DT * c1, -DT * c2, -DT * c3);
        tabB[iv] = -DT * c4;
    }
}

// broadcast lane L (0..15) of each 16-lane row to the whole row (VALU DPP16)
template <int L>
__device__ __forceinline__ float rb(float v) {
    const int s = __float_as_int(v);
    return __int_as_float(
        __builtin_amdgcn_update_dpp(s, s, 0x150 | L, 0xf, 0xf, false));
}

// ---- stage 2: main recurrence ----------------------------------------------
__global__ __launch_bounds__(256, 1) void lugre_kernel(
    const float* __restrict__ x,       // [B, T, 3]
    const float* __restrict__ sigma1,
    const float* __restrict__ sigma2,
    const float* __restrict__ alpha_p,
    const float* __restrict__ vs_p,
    const float4* __restrict__ tabA,   // [NV]
    const float*  __restrict__ tabB,   // [NV]
    float* __restrict__ out,           // [B, T]
    int B, int T)
{
    __shared__ float4 sA[NV];                       // 4096 B lerp table
    __shared__ float  sB[NV];                       // 1024 B

    const int tid = threadIdx.x;
    if (tid < NV) { sA[tid] = tabA[tid]; sB[tid] = tabB[tid]; }

    const int lane16 = tid & 15;          // step owner within 16-lane group
    const int grp    = (tid >> 4) & 3;    // 4 groups (sequences) per wave
    const int w      = tid >> 6;          // wave within block
    const int b      = blockIdx.x * 16 + w * 4 + grp;
    const int NB     = T / 16;            // 128 blocks of 16 steps

    const float LOG2E = 1.4426950408889634f;
    const float s1v    = fabsf(sigma1[0]);
    const float s2v    = fabsf(sigma2[0]);
    const float s12    = s1v + s2v;
    const float alpha  = alpha_p[0];
    const float inv_vs = 1.0f / vs_p[0];
    const float SVC    = (NV - 1) / (VMAXF - VMINF);
    const float VOFF   = -VMINF * SVC;    // 127.5
    const float IMAX   = 254.999f;

    const float* __restrict__ xb = x + (size_t)b * T * 3;
    float* __restrict__ outb = out + (size_t)b * T;

    // LDS lerp-table gather for this lane's step (off the sz chain)
    auto gather = [&](float v, float4& A0, float4& A1,
                      float& B0, float& B1, float& fr) {
        const float fvr = __builtin_amdgcn_fmed3f(fmaf(v, SVC, VOFF), 0.f, IMAX);
        const float fvf = floorf(fvr);
        fr = fvr - fvf;
        const int iv = (int)fvf;
        A0 = sA[iv]; A1 = sA[iv + 1];
        B0 = sB[iv]; B1 = sB[iv + 1];
    };

    // mkpre for this lane's step: lerp + premultiply -> payload in registers
    auto finish = [&](float v, float fc, float fs,
                      const float4& A0, const float4& A1,
                      float B0, float B1, float fr,
                      float& e0, float& e1, float& e2, float& e3, float& e4,
                      float& kk, float& ff, float& oQ, float& oSv) {
        const float av = fabsf(v);
        const float u  = av * inv_vs;
        const float lg = __builtin_amdgcn_logf(u);            // log2(u)
        const float pw = __builtin_amdgcn_exp2f(alpha * lg);  // u^alpha
        const float w_ = __builtin_amdgcn_exp2f(-LOG2E * pw); // exp(-u^alpha)
        const float g  = fmaf(fs - fc, w_, fc);
        kk = copysignf(g, v);
        const float avg = av * __builtin_amdgcn_rcpf(g);
        e0 = fmaf(fr, A1.x - A0.x, A0.x) * avg;
        e1 = fmaf(fr, A1.y - A0.y, A0.y) * avg;
        e2 = fmaf(fr, A1.z - A0.z, A0.z) * avg;
        e3 = fmaf(fr, A1.w - A0.w, A0.w) * avg;
        e4 = fmaf(fr, B1 - B0, B0) * avg;
        ff = fs;
        oQ  = -(s1v * avg);      // F = oQ*szn + (oSv + clip(szn))
        oSv = s12 * v;
    };

    // x queues: xc = block n+1, xn = block n+2 (state at top of iter n)
    float xcv, xcc, xcf, xnv, xnc, xnf;
    // gather stage for block n+1 (consumed by this iter's finish)
    float4 gA0, gA1; float gB0, gB1, gfr;
    // current payload (block n): lane-own regs, row_newbcast at use
    float ce0, ce1, ce2, ce3, ce4, ck, cf, cQ, cSv;

    // prologue: x for blocks 0..2 (before the barrier), then table-dependent
    const float* p0 = xb + 3 * lane16;
    const float a0v = p0[0], a0c = p0[1], a0f = p0[2];
    const float* p1 = xb + 48 + 3 * lane16;
    xcv = p1[0]; xcc = p1[1]; xcf = p1[2];
    const float* p2 = xb + 96 + 3 * lane16;
    xnv = p2[0]; xnc = p2[1]; xnf = p2[2];

    __syncthreads();                      // table resident

    {
        float4 aA0, aA1; float aB0, aB1, afr;
        gather(a0v, aA0, aA1, aB0, aB1, afr);
        finish(a0v, a0c, a0f, aA0, aA1, aB0, aB1, afr,
               ce0, ce1, ce2, ce3, ce4, ck, cf, cQ, cSv);
        gather(xcv, gA0, gA1, gB0, gB1, gfr);
    }

    float sz = 0.f;

#define STEP(t) {                                                   \
        const float e0 = rb<t>(ce0), e1 = rb<t>(ce1);               \
        const float e2 = rb<t>(ce2), e3 = rb<t>(ce3);               \
        const float e4 = rb<t>(ce4), kk = rb<t>(ck), ff = rb<t>(cf);\
        const float t1  = fmaf(e1, sz, e0);                         \
        const float t2  = fmaf(e3, sz, e2);                         \
        const float z2  = sz * sz;                                  \
        const float smk = sz - kk;                                  \
        const float t12 = fmaf(t2, z2, t1);                         \
        const float z4  = z2 * z2;                                  \
        const float xd  = fmaf(e4, z4, t12);                        \
        const float u_  = fmaf(xd, 0.5f, 1.f);                      \
        const float w_  = xd * u_;                                  \
        const float szn = fmaf(smk, w_, sz);                        \
        sz = __builtin_amdgcn_fmed3f(szn, -ff, ff);                 \
        kept = (lane16 == t) ? szn : kept; }

#pragma unroll 2
    for (int n = 0; n < NB; ++n) {
        // x load for block n+3 (~2 iterations of lead time)
        const int bl = (n + 3 < NB) ? n + 3 : NB - 1;
        const float* xp = xb + 48 * bl + 3 * lane16;
        const float lv = xp[0], lc = xp[1], lf = xp[2];

        // table gather for block n+2 (lane-own v resident in xn regs)
        float4 nA0, nA1; float nB0, nB1, nfr;
        gather(xnv, nA0, nA1, nB0, nB1, nfr);

        // mkpre for block n+1 -> next payload (off the sz chain)
        float ne0, ne1, ne2, ne3, ne4, nk, nf, nQ, nSv;
        finish(xcv, xcc, xcf, gA0, gA1, gB0, gB1, gfr,
               ne0, ne1, ne2, ne3, ne4, nk, nf, nQ, nSv);

        // 16 chain steps on block n's payload (row_newbcast per step)
        float kept = 0.f;
        STEP(0);  STEP(1);  STEP(2);  STEP(3);
        STEP(4);  STEP(5);  STEP(6);  STEP(7);
        STEP(8);  STEP(9);  STEP(10); STEP(11);
        STEP(12); STEP(13); STEP(14); STEP(15);

        // F for this lane's own step of block n (cf is lane-own payload fs)
        const float cl = __builtin_amdgcn_fmed3f(kept, -cf, cf);
        outb[16 * n + lane16] = fmaf(cQ, kept, cSv + cl);

        // rotate pipelines
        xcv = xnv; xcc = xnc; xcf = xnf;
        xnv = lv;  xnc = lc;  xnf = lf;
        gA0 = nA0; gA1 = nA1; gB0 = nB0; gB1 = nB1; gfr = nfr;
        ce0 = ne0; ce1 = ne1; ce2 = ne2; ce3 = ne3; ce4 = ne4;
        ck = nk; cf = nf; cQ = nQ; cSv = nSv;
    }
#undef STEP
}

extern "C" void kernel_launch(void* const* d_in, const int* in_sizes, int n_in,
                              void* d_out, int out_size, void* d_ws, size_t ws_size,
                              hipStream_t stream) {
    const float* x  = (const float*)d_in[0];
    const float* s1 = (const float*)d_in[1];
    const float* s2 = (const float*)d_in[2];
    const float* al = (const float*)d_in[3];
    const float* vs = (const float*)d_in[4];
    const float* W1 = (const float*)d_in[5];
    const float* b1 = (const float*)d_in[6];
    const float* W2 = (const float*)d_in[7];
    const float* b2 = (const float*)d_in[8];
    float* out = (float*)d_out;

    float4* tabA = (float4*)d_ws;                       // 4096 B
    float*  tabB = (float*)((char*)d_ws + NV * 16);     // 1024 B

    const int T = 2048;
    const int B = out_size / T;               // 4096

    coef_kernel<<<NV, 320, 0, stream>>>(W1, b1, W2, b2, tabA, tabB);
    lugre_kernel<<<B / 16, 256, 0, stream>>>(x, s1, s2, al, vs, tabA, tabB,
                                             out, B, T);
}